// Round 15
// baseline (350.393 us; speedup 1.0000x reference)
//
#include <hip/hip_runtime.h>
#include <hip/hip_bf16.h>
#include <math.h>

// ---------------------------------------------------------------------------
// VQ quantizer + 6-layer ReLU MLP via split-bf16 MFMA.
//   f32 GEMM ~= Ah*Bh + Ah*Bl + Al*Bh  (drop lo*lo ~2^-16 rel)
//   R15: R10 base (212.2us) +
//     (1) quantize quad-packed codebook rows: 9 ds_read_b128 per 4 codes
//         (2.25 DS/code vs 3) -- DS-pipe-bound fix, bits identical.
//     (2) mids: combine fused into gemm_mid (first-writer/second-combiner,
//         agent-scope atomics + fences; sum order p0+p1+bias == R10 bits);
//         h planes ping-pong A<->B (removes in-place hazard).
//     (3) L6: last-finisher combine (8 slices, bias+ascending order).
// Workspace map (<=41MB proven):
//   [0..8M)   phase1: qhi@0(1M), wihi@1M, wilo@3M (dead after L1)
//             phase2: midP tile partials (8M)
//             phase3: wohi@0(2M), wolo@2M
//   [8..16M)  hB planes: hBhi@8M, hBlo@12M
//   [16..24M) hA planes: hAhi@16M, hAlo@20M
//   [24..40M) whhi@24M, whlo@32M (dead after mids) -> phase3: l6par@24M(16M)
//   [40M..+8K) flags (zeroed each call via hipMemsetAsync)
// ---------------------------------------------------------------------------

#define B_ROWS 1024
#define D_IN   512
#define HDIM   2048
#define NTOT   (B_ROWS * D_IN)
#define NCODE  256
#define EDIM   8

typedef __attribute__((ext_vector_type(8))) short bf16x8;
typedef __attribute__((ext_vector_type(4))) float f32x4;

__device__ inline void gload_lds16(const void* g, void* l) {
    __builtin_amdgcn_global_load_lds(
        (const __attribute__((address_space(1))) void*)g,
        (__attribute__((address_space(3))) void*)l, 16, 0, 0);
}

__device__ inline ushort bf16_hi_bits(float v, float* hi_f) {
    __hip_bfloat16 h = __float2bfloat16(v);
    *hi_f = __bfloat162float(h);
    ushort u; __builtin_memcpy(&u, &h, 2); return u;
}
__device__ inline ushort bf16_bits(float v) {
    __hip_bfloat16 h = __float2bfloat16(v);
    ushort u; __builtin_memcpy(&u, &h, 2); return u;
}

// ---------------- fused: quantize (blocks 0..1023) + wi/wh split -------------
// Quantize: E=2 (proven occupancy), quad-packed codebook. Per-k distance bits
// identical to R10: d = RN(RN(sm+E[k]) - dot2), dot2 = sequential FMA of
// p2*w, p2 = 2*p (exact pow2 fold). k ascending, first-index-wins.
__global__ __launch_bounds__(256) void fused_pre(
    const float* __restrict__ x, const float* __restrict__ embW,
    const float* __restrict__ Wi, const float* __restrict__ Wh,
    ushort* __restrict__ qhi,
    ushort* __restrict__ wihi, ushort* __restrict__ wilo,
    ushort* __restrict__ whhi, ushort* __restrict__ whlo,
    float* __restrict__ loss_out)
{
    __shared__ float sQ[64][40];   // group g: w[e][u] at e*4+u (u = code%4), E at 32+u
    const int tid = threadIdx.x;

    if (blockIdx.x >= 1024) {
        // ---- weight split: 1280 blocks x 256 thr x 4 float4 ----
        const int sidx = blockIdx.x - 1024;
        #pragma unroll
        for (int s = 0; s < 4; ++s) {
            const int g = sidx * 1024 + s * 256 + tid;   // < 1310720
            const float* src; ushort* hi; ushort* lo; int j;
            if (g < 262144) { src = Wi; hi = wihi; lo = wilo; j = g; }
            else            { src = Wh; hi = whhi; lo = whlo; j = g - 262144; }
            float4 v = reinterpret_cast<const float4*>(src)[j];
            float f[4] = {v.x, v.y, v.z, v.w};
            ushort hh[4], ll[4];
            #pragma unroll
            for (int c = 0; c < 4; ++c) {
                float hf;
                hh[c] = bf16_hi_bits(f[c], &hf);
                ll[c] = bf16_bits(f[c] - hf);
            }
            ushort4 h4 = {hh[0], hh[1], hh[2], hh[3]};
            ushort4 l4 = {ll[0], ll[1], ll[2], ll[3]};
            reinterpret_cast<ushort4*>(hi)[j] = h4;
            reinterpret_cast<ushort4*>(lo)[j] = l4;
        }
        return;
    }

    // ---- build quad-packed codebook (thread tid = code tid) ----
    {
        const int c = tid, g = c >> 2, u = c & 3;
        const float4 a4 = *reinterpret_cast<const float4*>(&embW[c * EDIM]);
        const float4 b4 = *reinterpret_cast<const float4*>(&embW[c * EDIM + 4]);
        float s0 = __fmul_rn(a4.x, a4.x), s1 = __fmul_rn(a4.y, a4.y);
        float s2 = __fmul_rn(a4.z, a4.z), s3 = __fmul_rn(a4.w, a4.w);
        float s4 = __fmul_rn(b4.x, b4.x), s5 = __fmul_rn(b4.y, b4.y);
        float s6 = __fmul_rn(b4.z, b4.z), s7 = __fmul_rn(b4.w, b4.w);
        float a = __fadd_rn(__fadd_rn(s0, s1), __fadd_rn(s2, s3));
        float b = __fadd_rn(__fadd_rn(s4, s5), __fadd_rn(s6, s7));
        sQ[g][0 * 4 + u] = a4.x; sQ[g][1 * 4 + u] = a4.y;
        sQ[g][2 * 4 + u] = a4.z; sQ[g][3 * 4 + u] = a4.w;
        sQ[g][4 * 4 + u] = b4.x; sQ[g][5 * 4 + u] = b4.y;
        sQ[g][6 * 4 + u] = b4.z; sQ[g][7 * 4 + u] = b4.w;
        sQ[g][32 + u]    = __fadd_rn(a, b);        // E, numpy pairwise order
    }
    __syncthreads();

    const int nbase = blockIdx.x * 512 + tid;      // elems nbase, nbase+256

    float p2[2][EDIM], sm[2];
    #pragma unroll
    for (int j = 0; j < 2; ++j) {
        const float v = x[nbase + j * 256];
        float p[EDIM];
        #pragma unroll
        for (int e = 0; e < EDIM; ++e)
            p[e] = powf(v, (float)(e + 1));        // match np.power f32
        float a = __fadd_rn(__fadd_rn(p[0], p[1]), __fadd_rn(p[2], p[3]));
        float b = __fadd_rn(__fadd_rn(p[4], p[5]), __fadd_rn(p[6], p[7]));
        sm[j] = __fadd_rn(a, b);
        #pragma unroll
        for (int e = 0; e < EDIM; ++e)
            p2[j][e] = 2.0f * p[e];                // exact pow2 fold
    }

    float best[2] = {INFINITY, INFINITY};
    int   bi[2]   = {0, 0};

    #pragma unroll 2
    for (int g = 0; g < 64; ++g) {
        const f32x4* q4 = reinterpret_cast<const f32x4*>(sQ[g]);
        f32x4 ce[9];
        #pragma unroll
        for (int e = 0; e < 9; ++e) ce[e] = q4[e];
        #pragma unroll
        for (int u = 0; u < 4; ++u) {
            const int k = g * 4 + u;
            const float Ek = ce[8][u];
            #pragma unroll
            for (int j = 0; j < 2; ++j) {
                float dot = 0.f;
                dot = fmaf(p2[j][0], ce[0][u], dot);
                dot = fmaf(p2[j][1], ce[1][u], dot);
                dot = fmaf(p2[j][2], ce[2][u], dot);
                dot = fmaf(p2[j][3], ce[3][u], dot);
                dot = fmaf(p2[j][4], ce[4][u], dot);
                dot = fmaf(p2[j][5], ce[5][u], dot);
                dot = fmaf(p2[j][6], ce[6][u], dot);
                dot = fmaf(p2[j][7], ce[7][u], dot);
                float d = __fsub_rn(__fadd_rn(sm[j], Ek), dot);
                if (d < best[j]) { best[j] = d; bi[j] = k; }   // first-index-wins
            }
        }
    }

    #pragma unroll
    for (int j = 0; j < 2; ++j) {
        const int n  = nbase + j * 256;
        const int bo = n & (B_ROWS - 1);
        const int dd = n >> 10;
        qhi[bo * D_IN + dd] = bf16_bits((float)bi[j]);     // 0..255 exact bf16
    }
    if (blockIdx.x == 0 && tid == 0) loss_out[0] = 0.0f;
}

// ---------------- wo split (after mids; writes into freed phase-3 region) ----
__global__ __launch_bounds__(256) void wo_split(
    const float* __restrict__ Wo, ushort* __restrict__ hi, ushort* __restrict__ lo)
{
    const int tid = threadIdx.x;
    #pragma unroll
    for (int s = 0; s < 4; ++s) {
        const int j = blockIdx.x * 1024 + s * 256 + tid;   // < 262144
        float4 v = reinterpret_cast<const float4*>(Wo)[j];
        float f[4] = {v.x, v.y, v.z, v.w};
        ushort hh[4], ll[4];
        #pragma unroll
        for (int c = 0; c < 4; ++c) {
            float hf;
            hh[c] = bf16_hi_bits(f[c], &hf);
            ll[c] = bf16_bits(f[c] - hf);
        }
        ushort4 h4 = {hh[0], hh[1], hh[2], hh[3]};
        ushort4 l4 = {ll[0], ll[1], ll[2], ll[3]};
        reinterpret_cast<ushort4*>(hi)[j] = h4;
        reinterpret_cast<ushort4*>(lo)[j] = l4;
    }
}

// ---------------- L1 GEMM (R3-proven): block 64x128, wave 32x64, BK=64 -------
template<bool ALO, bool PARTIAL>
__global__ __launch_bounds__(256) void gemm_split(
    const ushort* __restrict__ Ahi, const ushort* __restrict__ Alo,
    const ushort* __restrict__ Whi, const ushort* __restrict__ Wlo,
    const float* __restrict__ bias,
    ushort* __restrict__ Ohi, ushort* __restrict__ Olo,
    float* __restrict__ OF, int N, int K, int klen)
{
    constexpr int BUF = 49152;
    constexpr int OFF_AH = 0, OFF_AL = 8192, OFF_BH = 16384;
    __shared__ char lds[2 * BUF];

    const int tid = threadIdx.x, lane = tid & 63, wid = tid >> 6;

    const int gy = gridDim.y;
    const int nwg = gridDim.x * gy;
    int lin = blockIdx.x * gy + blockIdx.y;
    int q   = nwg >> 3;
    int sw  = (lin & 7) * q + (lin >> 3);
    int bx  = sw / gy, by2 = sw % gy;
    const int bm   = (by2 & 15) << 6;
    const int kz   = by2 >> 4;
    const int kbeg = kz * klen;
    const int bn   = bx << 7;

    const int wm = (wid >> 1) << 5;
    const int wn = (wid & 1) << 6;

    constexpr int NSEGW = ALO ? 12 : 10;
    const ushort* gp[NSEGW];
    uint ldsoff[NSEGW];
    #pragma unroll
    for (int i = 0; i < NSEGW; ++i) {
        int s = wid + i * 4;
        const ushort* pl; int row0, base, sip;
        if (ALO) {
            if (s < 8)       { pl = Ahi; row0 = bm; base = OFF_AH;         sip = s; }
            else if (s < 16) { pl = Alo; row0 = bm; base = OFF_AL;         sip = s - 8; }
            else if (s < 32) { pl = Whi; row0 = bn; base = OFF_BH;         sip = s - 16; }
            else             { pl = Wlo; row0 = bn; base = OFF_BH + 16384; sip = s - 32; }
        } else {
            if (s < 8)       { pl = Ahi; row0 = bm; base = OFF_AH;         sip = s; }
            else if (s < 24) { pl = Whi; row0 = bn; base = OFF_BH;         sip = s - 8; }
            else             { pl = Wlo; row0 = bn; base = OFF_BH + 16384; sip = s - 24; }
        }
        int r  = sip * 8 + (lane >> 3);
        int ch = (lane & 7) ^ (r & 7);
        gp[i]     = pl + (size_t)(row0 + r) * K + kbeg + ch * 8;
        ldsoff[i] = base + sip * 1024;
    }

    uint aoff[2][2], boff[4][2];
    #pragma unroll
    for (int f = 0; f < 2; ++f) {
        int ar = wm + f * 16 + (lane & 15);
        #pragma unroll
        for (int s = 0; s < 2; ++s) {
            int ch = (s * 4 + (lane >> 4)) ^ (ar & 7);
            aoff[f][s] = OFF_AH + ar * 128 + ch * 16;
        }
    }
    #pragma unroll
    for (int f = 0; f < 4; ++f) {
        int br = wn + f * 16 + (lane & 15);
        #pragma unroll
        for (int s = 0; s < 2; ++s) {
            int ch = (s * 4 + (lane >> 4)) ^ (br & 7);
            boff[f][s] = OFF_BH + br * 128 + ch * 16;
        }
    }

    auto stage = [&](int kt, int b) {
        #pragma unroll
        for (int i = 0; i < NSEGW; ++i)
            gload_lds16(gp[i] + kt * 64, lds + b * BUF + ldsoff[i]);
    };

    f32x4 acc[2][4] = {};
    const int NT = klen >> 6;

    stage(0, 0);
    __syncthreads();

    for (int t = 0; t < NT; ++t) {
        const int cur = t & 1;
        if (t + 1 < NT) stage(t + 1, cur ^ 1);

        const char* lb = lds + cur * BUF;
        bf16x8 aH[2][2], aL[2][2], bH[2][4], bL[2][4];
        #pragma unroll
        for (int s = 0; s < 2; ++s) {
            #pragma unroll
            for (int f = 0; f < 2; ++f) {
                aH[s][f] = *(const bf16x8*)(lb + aoff[f][s]);
                if constexpr (ALO) aL[s][f] = *(const bf16x8*)(lb + aoff[f][s] + 8192);
            }
            #pragma unroll
            for (int f = 0; f < 4; ++f) {
                bH[s][f] = *(const bf16x8*)(lb + boff[f][s]);
                bL[s][f] = *(const bf16x8*)(lb + boff[f][s] + 16384);
            }
        }
        #pragma unroll
        for (int s = 0; s < 2; ++s) {
            #pragma unroll
            for (int fm = 0; fm < 2; ++fm)
                #pragma unroll
                for (int fn = 0; fn < 4; ++fn)
                    acc[fm][fn] = __builtin_amdgcn_mfma_f32_16x16x32_bf16(
                        aH[s][fm], bH[s][fn], acc[fm][fn], 0, 0, 0);
            #pragma unroll
            for (int fm = 0; fm < 2; ++fm)
                #pragma unroll
                for (int fn = 0; fn < 4; ++fn)
                    acc[fm][fn] = __builtin_amdgcn_mfma_f32_16x16x32_bf16(
                        aH[s][fm], bL[s][fn], acc[fm][fn], 0, 0, 0);
            if constexpr (ALO) {
                #pragma unroll
                for (int fm = 0; fm < 2; ++fm)
                    #pragma unroll
                    for (int fn = 0; fn < 4; ++fn)
                        acc[fm][fn] = __builtin_amdgcn_mfma_f32_16x16x32_bf16(
                            aL[s][fm], bH[s][fn], acc[fm][fn], 0, 0, 0);
            }
        }
        __syncthreads();
    }

    #pragma unroll
    for (int fm = 0; fm < 2; ++fm) {
        #pragma unroll
        for (int fn = 0; fn < 4; ++fn) {
            const int col = bn + wn + fn * 16 + (lane & 15);
            const int rb  = bm + wm + fm * 16 + ((lane >> 4) << 2);
            if constexpr (PARTIAL) {
                #pragma unroll
                for (int r = 0; r < 4; ++r)
                    OF[(size_t)(kz * B_ROWS + rb + r) * N + col] = acc[fm][fn][r];
            } else {
                const float bc = bias[col];
                #pragma unroll
                for (int r = 0; r < 4; ++r) {
                    float v = acc[fm][fn][r] + bc;
                    v = v > 0.f ? v : 0.f;
                    float hf;
                    ushort hb = bf16_hi_bits(v, &hf);
                    Ohi[(size_t)(rb + r) * N + col] = hb;
                    Olo[(size_t)(rb + r) * N + col] = bf16_bits(v - hf);
                }
            }
        }
    }
}

// ---------------- mid/L6 GEMM with FUSED combine -----------------------------
// Main loop = R5/R10-proven 128x128, wave 64x64, BK=64, 2-phase dbuf.
// MID (NSPLIT=2): first-writer/second-combiner; partials tile-contiguous in P
//   (128 tiles x 64KB). Sum order p0+p1+bias (== R10 combine bits).
// L6 (NSPLIT=8): all write slices P[z*32+tile]; last finisher combines
//   bias + slices ascending (== R10 combine_relu bits).
template<int NSPLIT, bool MID>
__global__ __launch_bounds__(256) void gemm_mid(
    const ushort* __restrict__ Ahi, const ushort* __restrict__ Alo,
    const ushort* __restrict__ Bhi, const ushort* __restrict__ Blo,
    float* __restrict__ P, const float* __restrict__ bias,
    ushort* __restrict__ Ohi, ushort* __restrict__ Olo,
    float* __restrict__ OUT, uint* __restrict__ flags,
    int N, int Kfull, int klen)
{
    constexpr int BUF = 65536;
    constexpr int OFF_A[2] = {0, 16384};
    constexpr int OFF_B[2] = {32768, 49152};
    __shared__ char lds[2 * BUF];

    const int tid = threadIdx.x, lane = tid & 63, wid = tid >> 6;

    const int gy = gridDim.y;
    const int nwg = gridDim.x * gy;
    int lin = blockIdx.x * gy + blockIdx.y;
    int q   = nwg >> 3;
    int sw  = (lin & 7) * q + (lin >> 3);
    int bx  = sw / gy, by2 = sw % gy;
    const int bm   = (by2 & 7) << 7;
    const int kz   = by2 >> 3;
    const int kbeg = kz * klen;
    const int bn   = bx << 7;

    const int wm = (wid >> 1) << 6;
    const int wn = (wid & 1) << 6;

    const int ch0 = (lane & 7) ^ (lane >> 3);
    const size_t kstep8 = (size_t)Kfull * 8;
    const ushort* gpb[4];
    uint lob[4];
    {
        const ushort* pls[4] = {Ahi, Alo, Bhi, Blo};
        const int row0s[4]   = {bm, bm, bn, bn};
        const uint bases[4]  = {OFF_A[0], OFF_A[1], OFF_B[0], OFF_B[1]};
        #pragma unroll
        for (int p = 0; p < 4; ++p) {
            gpb[p] = pls[p] + (size_t)(row0s[p] + wid * 32 + (lane >> 3)) * Kfull
                     + kbeg + ch0 * 8;
            lob[p] = bases[p] + wid * 4096;
        }
    }

    uint aoff[4][2], boff[4][2];
    #pragma unroll
    for (int f = 0; f < 4; ++f) {
        #pragma unroll
        for (int ks = 0; ks < 2; ++ks) {
            int ch = (ks * 4 + (lane >> 4)) ^ (lane & 7);
            aoff[f][ks] = OFF_A[0] + (wm + f * 16 + (lane & 15)) * 128 + ch * 16;
            boff[f][ks] = OFF_B[0] + (wn + f * 16 + (lane & 15)) * 128 + ch * 16;
        }
    }

    auto stage = [&](int kt, int b) {
        #pragma unroll
        for (int p = 0; p < 4; ++p)
            #pragma unroll
            for (int i = 0; i < 4; ++i)
                gload_lds16(gpb[p] + i * kstep8 + kt * 64,
                            lds + b * BUF + lob[p] + i * 1024);
    };

    f32x4 acc[4][4] = {};
    const int NT = klen >> 6;

    stage(0, 0);
    __syncthreads();

    for (int t = 0; t < NT; ++t) {
        const int cur = t & 1;
        if (t + 1 < NT) stage(t + 1, cur ^ 1);

        const char* lb = lds + cur * BUF;
        #pragma unroll
        for (int ks = 0; ks < 2; ++ks) {
            bf16x8 aH[4], aL[4], bH[4], bL[4];
            #pragma unroll
            for (int f = 0; f < 4; ++f) {
                aH[f] = *(const bf16x8*)(lb + aoff[f][ks]);
                aL[f] = *(const bf16x8*)(lb + aoff[f][ks] + 16384);
                bH[f] = *(const bf16x8*)(lb + boff[f][ks]);
                bL[f] = *(const bf16x8*)(lb + boff[f][ks] + 16384);
            }
            #pragma unroll
            for (int fm = 0; fm < 4; ++fm)
                #pragma unroll
                for (int fn = 0; fn < 4; ++fn)
                    acc[fm][fn] = __builtin_amdgcn_mfma_f32_16x16x32_bf16(
                        aH[fm], bH[fn], acc[fm][fn], 0, 0, 0);
            #pragma unroll
            for (int fm = 0; fm < 4; ++fm)
                #pragma unroll
                for (int fn = 0; fn < 4; ++fn)
                    acc[fm][fn] = __builtin_amdgcn_mfma_f32_16x16x32_bf16(
                        aH[fm], bL[fn], acc[fm][fn], 0, 0, 0);
            #pragma unroll
            for (int fm = 0; fm < 4; ++fm)
                #pragma unroll
                for (int fn = 0; fn < 4; ++fn)
                    acc[fm][fn] = __builtin_amdgcn_mfma_f32_16x16x32_bf16(
                        aL[fm], bH[fn], acc[fm][fn], 0, 0, 0);
        }
        __syncthreads();
    }

    const int tile = bx * 8 + (by2 & 7);

    if constexpr (MID) {
        __shared__ int role;
        if (tid == 0) {
            uint old = __hip_atomic_fetch_add(&flags[tile], 1u,
                           __ATOMIC_RELAXED, __HIP_MEMORY_SCOPE_AGENT);
            role = (int)old;
        }
        __syncthreads();
        float* tp = P + (size_t)tile * 16384;
        if (role == 0) {
            // first finisher: publish partial, release-flag, exit
            #pragma unroll
            for (int fm = 0; fm < 4; ++fm)
                #pragma unroll
                for (int fn = 0; fn < 4; ++fn) {
                    const int lc  = wn + fn * 16 + (lane & 15);
                    const int lr0 = wm + fm * 16 + ((lane >> 4) << 2);
                    #pragma unroll
                    for (int r = 0; r < 4; ++r)
                        tp[(lr0 + r) * 128 + lc] = acc[fm][fn][r];
                }
            __syncthreads();                 // drains all waves' stores (vmcnt0)
            if (tid == 0) {
                __threadfence();             // flush to device scope
                __hip_atomic_store(&flags[128 + tile], 1u,
                                   __ATOMIC_RELEASE, __HIP_MEMORY_SCOPE_AGENT);
            }
            return;
        }
        // second finisher: wait for peer's partial (peer is resident -> no deadlock)
        if (tid == 0) {
            while (__hip_atomic_load(&flags[128 + tile],
                       __ATOMIC_ACQUIRE, __HIP_MEMORY_SCOPE_AGENT) == 0u)
                __builtin_amdgcn_s_sleep(2);
            __threadfence();                 // invalidate caches before reads
        }
        __syncthreads();
        #pragma unroll
        for (int fm = 0; fm < 4; ++fm)
            #pragma unroll
            for (int fn = 0; fn < 4; ++fn) {
                const int lc  = wn + fn * 16 + (lane & 15);
                const int gc  = bn + lc;
                const float bc = bias[gc];
                const int lr0 = wm + fm * 16 + ((lane >> 4) << 2);
                #pragma unroll
                for (int r = 0; r < 4; ++r) {
                    const float other = tp[(lr0 + r) * 128 + lc];
                    // fixed order p0 + p1, then +bias (== R10 combine bits)
                    float v = (kz == 0) ? (acc[fm][fn][r] + other)
                                        : (other + acc[fm][fn][r]);
                    v = v + bc;
                    v = v > 0.f ? v : 0.f;
                    float hf;
                    ushort hb = bf16_hi_bits(v, &hf);
                    const size_t o = (size_t)(bm + lr0 + r) * N + gc;
                    Ohi[o] = hb;
                    Olo[o] = bf16_bits(v - hf);
                }
            }
        return;
    } else {
        // L6: write tile-contiguous slice, last finisher combines
        float* tp = P + ((size_t)kz * 32 + tile) * 16384;
        #pragma unroll
        for (int fm = 0; fm < 4; ++fm)
            #pragma unroll
            for (int fn = 0; fn < 4; ++fn) {
                const int lc  = wn + fn * 16 + (lane & 15);
                const int lr0 = wm + fm * 16 + ((lane >> 4) << 2);
                #pragma unroll
                for (int r = 0; r < 4; ++r)
                    tp[(lr0 + r) * 128 + lc] = acc[fm][fn][r];
            }
        __shared__ int isLast;
        __syncthreads();                     // drains all waves' stores
        if (tid == 0) {
            __threadfence();
            uint old = __hip_atomic_fetch_add(&flags[tile], 1u,
                           __ATOMIC_ACQ_REL, __HIP_MEMORY_SCOPE_AGENT);
            isLast = (old == (uint)(NSPLIT - 1));
            if (isLast) __threadfence();     // invalidate before reads
        }
        __syncthreads();
        if (!isLast) return;
        for (int i = tid; i < 4096; i += 256) {
            const int r  = i >> 5;
            const int c4 = (i & 31) << 2;
            const int gc = bn + c4;
            float4 bb = *reinterpret_cast<const float4*>(&bias[gc]);
            float s0 = bb.x, s1 = bb.y, s2 = bb.z, s3 = bb.w;
            #pragma unroll
            for (int z = 0; z < NSPLIT; ++z) {
                const float4 p = *reinterpret_cast<const float4*>(
                    P + ((size_t)z * 32 + tile) * 16384 + (size_t)i * 4);
                s0 += p.x; s1 += p.y; s2 += p.z; s3 += p.w;
            }
            float4 o;
            o.x = s0 > 0.f ? s0 : 0.f;
            o.y = s1 > 0.f ? s1 : 0.f;
            o.z = s2 > 0.f ? s2 : 0.f;
            o.w = s3 > 0.f ? s3 : 0.f;
            *reinterpret_cast<float4*>(&OUT[(size_t)(bm + r) * N + gc]) = o;
        }
        return;
    }
}

// ---------------------------------------------------------------------------
extern "C" void kernel_launch(void* const* d_in, const int* in_sizes, int n_in,
                              void* d_out, int out_size, void* d_ws, size_t ws_size,
                              hipStream_t stream)
{
    const float* x     = (const float*)d_in[0];
    const float* emb_W = (const float*)d_in[1];
    const float* W_in  = (const float*)d_in[2];
    const float* b_in  = (const float*)d_in[3];
    const float* W_h   = (const float*)d_in[4];
    const float* b_h   = (const float*)d_in[5];
    const float* W_out = (const float*)d_in[6];
    const float* b_out = (const float*)d_in[7];
    float* out = (float*)d_out;

    char* w = (char*)d_ws;
    const size_t MB = 1 << 20;
    // [0..8M) phase region
    ushort* qhi   = (ushort*)(w);             // 1MB  (phase 1)
    ushort* wihi  = (ushort*)(w + 1*MB);      // 2MB  (phase 1)
    ushort* wilo  = (ushort*)(w + 3*MB);      // 2MB  (phase 1)
    float*  midP  = (float*)(w);              // 8MB  (phase 2: 128 tiles x 64KB)
    ushort* wohi  = (ushort*)(w);             // 2MB  (phase 3)
    ushort* wolo  = (ushort*)(w + 2*MB);      // 2MB  (phase 3)
    // h plane ping-pong
    ushort* hBhi  = (ushort*)(w + 8*MB);      // 4MB
    ushort* hBlo  = (ushort*)(w + 12*MB);     // 4MB
    ushort* hAhi  = (ushort*)(w + 16*MB);     // 4MB
    ushort* hAlo  = (ushort*)(w + 20*MB);     // 4MB
    // weights / L6 partials
    ushort* whhi  = (ushort*)(w + 24*MB);     // 8MB (dead after mids)
    ushort* whlo  = (ushort*)(w + 32*MB);     // 8MB (dead after mids)
    float*  l6par = (float*)(w + 24*MB);      // 16MB (phase 3: 8 x 32 x 64KB)
    uint*   flags = (uint*)(w + 40*MB);       // 8KB, zeroed every call

    // 0) zero sync flags (graph-capturable)
    hipMemsetAsync(flags, 0, 8192, stream);

    // 1) quantize + wi/wh split (fused); writes loss scalar at out[NTOT]
    fused_pre<<<2304, 256, 0, stream>>>(x, emb_W, W_in, W_h,
                                        qhi, wihi, wilo, whhi, whlo, out + NTOT);

    // 2) L1: hA = relu(q @ W_in^T + b_in)  M=1024 N=2048 K=512 (A exact, 2-term)
    gemm_split<false, false><<<dim3(16, 16), 256, 0, stream>>>(
        qhi, nullptr, wihi, wilo, b_in, hAhi, hAlo, nullptr, HDIM, D_IN, D_IN);

    // 3) 4x mid (splitK2, fused combine, ping-pong h planes)
    for (int l = 0; l < 4; ++l) {
        const ushort* ihi = (l & 1) ? hBhi : hAhi;
        const ushort* ilo = (l & 1) ? hBlo : hAlo;
        ushort* ohi = (l & 1) ? hAhi : hBhi;
        ushort* olo = (l & 1) ? hAlo : hBlo;
        gemm_mid<2, true><<<dim3(16, 16), 256, 0, stream>>>(
            ihi, ilo, whhi, whlo, midP, b_h, ohi, olo, nullptr,
            flags + l * 256, HDIM, HDIM, 1024);
    }
    // after l=3 result is in hA planes

    // 4) split W_out into freed phase-3 region
    wo_split<<<256, 256, 0, stream>>>(W_out, wohi, wolo);

    // 5) L6 (splitK8, fused last-finisher combine) -> d_out
    gemm_mid<8, false><<<dim3(4, 64), 256, 0, stream>>>(
        hAhi, hAlo, wohi, wolo, l6par, b_out, nullptr, nullptr, out,
        flags + 1024, D_IN, HDIM, 256);
}

// Round 16
// 210.829 us; speedup vs baseline: 1.6620x; 1.6620x over previous
//
#include <hip/hip_runtime.h>
#include <hip/hip_bf16.h>
#include <math.h>

// ---------------------------------------------------------------------------
// VQ quantizer + 6-layer ReLU MLP via split-bf16 MFMA.
//   f32 GEMM ~= Ah*Bh + Ah*Bl + Al*Bh  (drop lo*lo ~2^-16 rel)
//   R16: R10 exact (212.2us proven) + quantize quad-packed codebook
//        (9 ds_read_b128 per 4 codes = 2.25 DS/code vs 3; DS-pipe-bound fix;
//        verified correct inside R15). No other changes.
// Workspace map (40MB):
//   [0..16M)  phase1: qhi@0(1M), wihi@1M, wilo@3M   (dead after L1)
//             phase2: mid partial p0@0(8M), p1@8M
//             phase3: wohi@0(2M), wolo@2M
//   [16..24M) h planes: hhi@16M, hlo@20M
//   [24..40M) whhi@24M, whlo@32M (dead after mids) -> phase3: l6par@24M(16M)
// ---------------------------------------------------------------------------

#define B_ROWS 1024
#define D_IN   512
#define HDIM   2048
#define NTOT   (B_ROWS * D_IN)
#define NCODE  256
#define EDIM   8

typedef __attribute__((ext_vector_type(8))) short bf16x8;
typedef __attribute__((ext_vector_type(4))) float f32x4;

__device__ inline void gload_lds16(const void* g, void* l) {
    __builtin_amdgcn_global_load_lds(
        (const __attribute__((address_space(1))) void*)g,
        (__attribute__((address_space(3))) void*)l, 16, 0, 0);
}

__device__ inline ushort bf16_hi_bits(float v, float* hi_f) {
    __hip_bfloat16 h = __float2bfloat16(v);
    *hi_f = __bfloat162float(h);
    ushort u; __builtin_memcpy(&u, &h, 2); return u;
}
__device__ inline ushort bf16_bits(float v) {
    __hip_bfloat16 h = __float2bfloat16(v);
    ushort u; __builtin_memcpy(&u, &h, 2); return u;
}

// ---------------- fused: quantize (blocks 0..1023) + wi/wh split -------------
// Quantize: E=2 (proven occupancy), quad-packed codebook (R15-verified).
// Per-k distance bits identical to R10: d = RN(RN(sm+E[k]) - dot2),
// dot2 = sequential FMA of p2*w, p2 = 2*p. k ascending, first-index-wins.
__global__ __launch_bounds__(256) void fused_pre(
    const float* __restrict__ x, const float* __restrict__ embW,
    const float* __restrict__ Wi, const float* __restrict__ Wh,
    ushort* __restrict__ qhi,
    ushort* __restrict__ wihi, ushort* __restrict__ wilo,
    ushort* __restrict__ whhi, ushort* __restrict__ whlo,
    float* __restrict__ loss_out)
{
    __shared__ float sQ[64][40];   // group g: w[e][u] at e*4+u (u=code%4), E at 32+u
    const int tid = threadIdx.x;

    if (blockIdx.x >= 1024) {
        // ---- weight split: 1280 blocks x 256 thr x 4 float4 ----
        const int sidx = blockIdx.x - 1024;
        #pragma unroll
        for (int s = 0; s < 4; ++s) {
            const int g = sidx * 1024 + s * 256 + tid;   // < 1310720
            const float* src; ushort* hi; ushort* lo; int j;
            if (g < 262144) { src = Wi; hi = wihi; lo = wilo; j = g; }
            else            { src = Wh; hi = whhi; lo = whlo; j = g - 262144; }
            float4 v = reinterpret_cast<const float4*>(src)[j];
            float f[4] = {v.x, v.y, v.z, v.w};
            ushort hh[4], ll[4];
            #pragma unroll
            for (int c = 0; c < 4; ++c) {
                float hf;
                hh[c] = bf16_hi_bits(f[c], &hf);
                ll[c] = bf16_bits(f[c] - hf);
            }
            ushort4 h4 = {hh[0], hh[1], hh[2], hh[3]};
            ushort4 l4 = {ll[0], ll[1], ll[2], ll[3]};
            reinterpret_cast<ushort4*>(hi)[j] = h4;
            reinterpret_cast<ushort4*>(lo)[j] = l4;
        }
        return;
    }

    // ---- build quad-packed codebook (thread tid = code tid) ----
    {
        const int c = tid, g = c >> 2, u = c & 3;
        const float4 a4 = *reinterpret_cast<const float4*>(&embW[c * EDIM]);
        const float4 b4 = *reinterpret_cast<const float4*>(&embW[c * EDIM + 4]);
        float s0 = __fmul_rn(a4.x, a4.x), s1 = __fmul_rn(a4.y, a4.y);
        float s2 = __fmul_rn(a4.z, a4.z), s3 = __fmul_rn(a4.w, a4.w);
        float s4 = __fmul_rn(b4.x, b4.x), s5 = __fmul_rn(b4.y, b4.y);
        float s6 = __fmul_rn(b4.z, b4.z), s7 = __fmul_rn(b4.w, b4.w);
        float a = __fadd_rn(__fadd_rn(s0, s1), __fadd_rn(s2, s3));
        float b = __fadd_rn(__fadd_rn(s4, s5), __fadd_rn(s6, s7));
        sQ[g][0 * 4 + u] = a4.x; sQ[g][1 * 4 + u] = a4.y;
        sQ[g][2 * 4 + u] = a4.z; sQ[g][3 * 4 + u] = a4.w;
        sQ[g][4 * 4 + u] = b4.x; sQ[g][5 * 4 + u] = b4.y;
        sQ[g][6 * 4 + u] = b4.z; sQ[g][7 * 4 + u] = b4.w;
        sQ[g][32 + u]    = __fadd_rn(a, b);        // E, numpy pairwise order
    }
    __syncthreads();

    const int nbase = blockIdx.x * 512 + tid;      // elems nbase, nbase+256

    float p2[2][EDIM], sm[2];
    #pragma unroll
    for (int j = 0; j < 2; ++j) {
        const float v = x[nbase + j * 256];
        float p[EDIM];
        #pragma unroll
        for (int e = 0; e < EDIM; ++e)
            p[e] = powf(v, (float)(e + 1));        // match np.power f32
        float a = __fadd_rn(__fadd_rn(p[0], p[1]), __fadd_rn(p[2], p[3]));
        float b = __fadd_rn(__fadd_rn(p[4], p[5]), __fadd_rn(p[6], p[7]));
        sm[j] = __fadd_rn(a, b);
        #pragma unroll
        for (int e = 0; e < EDIM; ++e)
            p2[j][e] = 2.0f * p[e];                // exact pow2 fold
    }

    float best[2] = {INFINITY, INFINITY};
    int   bi[2]   = {0, 0};

    #pragma unroll 2
    for (int g = 0; g < 64; ++g) {
        const f32x4* q4 = reinterpret_cast<const f32x4*>(sQ[g]);
        f32x4 ce[9];
        #pragma unroll
        for (int e = 0; e < 9; ++e) ce[e] = q4[e];
        #pragma unroll
        for (int u = 0; u < 4; ++u) {
            const int k = g * 4 + u;
            const float Ek = ce[8][u];
            #pragma unroll
            for (int j = 0; j < 2; ++j) {
                float dot = 0.f;
                dot = fmaf(p2[j][0], ce[0][u], dot);
                dot = fmaf(p2[j][1], ce[1][u], dot);
                dot = fmaf(p2[j][2], ce[2][u], dot);
                dot = fmaf(p2[j][3], ce[3][u], dot);
                dot = fmaf(p2[j][4], ce[4][u], dot);
                dot = fmaf(p2[j][5], ce[5][u], dot);
                dot = fmaf(p2[j][6], ce[6][u], dot);
                dot = fmaf(p2[j][7], ce[7][u], dot);
                float d = __fsub_rn(__fadd_rn(sm[j], Ek), dot);
                if (d < best[j]) { best[j] = d; bi[j] = k; }   // first-index-wins
            }
        }
    }

    #pragma unroll
    for (int j = 0; j < 2; ++j) {
        const int n  = nbase + j * 256;
        const int bo = n & (B_ROWS - 1);
        const int dd = n >> 10;
        qhi[bo * D_IN + dd] = bf16_bits((float)bi[j]);     // 0..255 exact bf16
    }
    if (blockIdx.x == 0 && tid == 0) loss_out[0] = 0.0f;
}

// ---------------- wo split (after mids; writes into freed phase-3 region) ----
__global__ __launch_bounds__(256) void wo_split(
    const float* __restrict__ Wo, ushort* __restrict__ hi, ushort* __restrict__ lo)
{
    const int tid = threadIdx.x;
    #pragma unroll
    for (int s = 0; s < 4; ++s) {
        const int j = blockIdx.x * 1024 + s * 256 + tid;   // < 262144
        float4 v = reinterpret_cast<const float4*>(Wo)[j];
        float f[4] = {v.x, v.y, v.z, v.w};
        ushort hh[4], ll[4];
        #pragma unroll
        for (int c = 0; c < 4; ++c) {
            float hf;
            hh[c] = bf16_hi_bits(f[c], &hf);
            ll[c] = bf16_bits(f[c] - hf);
        }
        ushort4 h4 = {hh[0], hh[1], hh[2], hh[3]};
        ushort4 l4 = {ll[0], ll[1], ll[2], ll[3]};
        reinterpret_cast<ushort4*>(hi)[j] = h4;
        reinterpret_cast<ushort4*>(lo)[j] = l4;
    }
}

// ---------------- L1 GEMM (R3-proven): block 64x128, wave 32x64, BK=64 -------
template<bool ALO, bool PARTIAL>
__global__ __launch_bounds__(256) void gemm_split(
    const ushort* __restrict__ Ahi, const ushort* __restrict__ Alo,
    const ushort* __restrict__ Whi, const ushort* __restrict__ Wlo,
    const float* __restrict__ bias,
    ushort* __restrict__ Ohi, ushort* __restrict__ Olo,
    float* __restrict__ OF, int N, int K, int klen)
{
    constexpr int BUF = 49152;
    constexpr int OFF_AH = 0, OFF_AL = 8192, OFF_BH = 16384;
    __shared__ char lds[2 * BUF];

    const int tid = threadIdx.x, lane = tid & 63, wid = tid >> 6;

    const int gy = gridDim.y;
    const int nwg = gridDim.x * gy;
    int lin = blockIdx.x * gy + blockIdx.y;
    int q   = nwg >> 3;
    int sw  = (lin & 7) * q + (lin >> 3);
    int bx  = sw / gy, by2 = sw % gy;
    const int bm   = (by2 & 15) << 6;
    const int kz   = by2 >> 4;
    const int kbeg = kz * klen;
    const int bn   = bx << 7;

    const int wm = (wid >> 1) << 5;
    const int wn = (wid & 1) << 6;

    constexpr int NSEGW = ALO ? 12 : 10;
    const ushort* gp[NSEGW];
    uint ldsoff[NSEGW];
    #pragma unroll
    for (int i = 0; i < NSEGW; ++i) {
        int s = wid + i * 4;
        const ushort* pl; int row0, base, sip;
        if (ALO) {
            if (s < 8)       { pl = Ahi; row0 = bm; base = OFF_AH;         sip = s; }
            else if (s < 16) { pl = Alo; row0 = bm; base = OFF_AL;         sip = s - 8; }
            else if (s < 32) { pl = Whi; row0 = bn; base = OFF_BH;         sip = s - 16; }
            else             { pl = Wlo; row0 = bn; base = OFF_BH + 16384; sip = s - 32; }
        } else {
            if (s < 8)       { pl = Ahi; row0 = bm; base = OFF_AH;         sip = s; }
            else if (s < 24) { pl = Whi; row0 = bn; base = OFF_BH;         sip = s - 8; }
            else             { pl = Wlo; row0 = bn; base = OFF_BH + 16384; sip = s - 24; }
        }
        int r  = sip * 8 + (lane >> 3);
        int ch = (lane & 7) ^ (r & 7);
        gp[i]     = pl + (size_t)(row0 + r) * K + kbeg + ch * 8;
        ldsoff[i] = base + sip * 1024;
    }

    uint aoff[2][2], boff[4][2];
    #pragma unroll
    for (int f = 0; f < 2; ++f) {
        int ar = wm + f * 16 + (lane & 15);
        #pragma unroll
        for (int s = 0; s < 2; ++s) {
            int ch = (s * 4 + (lane >> 4)) ^ (ar & 7);
            aoff[f][s] = OFF_AH + ar * 128 + ch * 16;
        }
    }
    #pragma unroll
    for (int f = 0; f < 4; ++f) {
        int br = wn + f * 16 + (lane & 15);
        #pragma unroll
        for (int s = 0; s < 2; ++s) {
            int ch = (s * 4 + (lane >> 4)) ^ (br & 7);
            boff[f][s] = OFF_BH + br * 128 + ch * 16;
        }
    }

    auto stage = [&](int kt, int b) {
        #pragma unroll
        for (int i = 0; i < NSEGW; ++i)
            gload_lds16(gp[i] + kt * 64, lds + b * BUF + ldsoff[i]);
    };

    f32x4 acc[2][4] = {};
    const int NT = klen >> 6;

    stage(0, 0);
    __syncthreads();

    for (int t = 0; t < NT; ++t) {
        const int cur = t & 1;
        if (t + 1 < NT) stage(t + 1, cur ^ 1);

        const char* lb = lds + cur * BUF;
        bf16x8 aH[2][2], aL[2][2], bH[2][4], bL[2][4];
        #pragma unroll
        for (int s = 0; s < 2; ++s) {
            #pragma unroll
            for (int f = 0; f < 2; ++f) {
                aH[s][f] = *(const bf16x8*)(lb + aoff[f][s]);
                if constexpr (ALO) aL[s][f] = *(const bf16x8*)(lb + aoff[f][s] + 8192);
            }
            #pragma unroll
            for (int f = 0; f < 4; ++f) {
                bH[s][f] = *(const bf16x8*)(lb + boff[f][s]);
                bL[s][f] = *(const bf16x8*)(lb + boff[f][s] + 16384);
            }
        }
        #pragma unroll
        for (int s = 0; s < 2; ++s) {
            #pragma unroll
            for (int fm = 0; fm < 2; ++fm)
                #pragma unroll
                for (int fn = 0; fn < 4; ++fn)
                    acc[fm][fn] = __builtin_amdgcn_mfma_f32_16x16x32_bf16(
                        aH[s][fm], bH[s][fn], acc[fm][fn], 0, 0, 0);
            #pragma unroll
            for (int fm = 0; fm < 2; ++fm)
                #pragma unroll
                for (int fn = 0; fn < 4; ++fn)
                    acc[fm][fn] = __builtin_amdgcn_mfma_f32_16x16x32_bf16(
                        aH[s][fm], bL[s][fn], acc[fm][fn], 0, 0, 0);
            if constexpr (ALO) {
                #pragma unroll
                for (int fm = 0; fm < 2; ++fm)
                    #pragma unroll
                    for (int fn = 0; fn < 4; ++fn)
                        acc[fm][fn] = __builtin_amdgcn_mfma_f32_16x16x32_bf16(
                            aL[s][fm], bH[s][fn], acc[fm][fn], 0, 0, 0);
            }
        }
        __syncthreads();
    }

    #pragma unroll
    for (int fm = 0; fm < 2; ++fm) {
        #pragma unroll
        for (int fn = 0; fn < 4; ++fn) {
            const int col = bn + wn + fn * 16 + (lane & 15);
            const int rb  = bm + wm + fm * 16 + ((lane >> 4) << 2);
            if constexpr (PARTIAL) {
                #pragma unroll
                for (int r = 0; r < 4; ++r)
                    OF[(size_t)(kz * B_ROWS + rb + r) * N + col] = acc[fm][fn][r];
            } else {
                const float bc = bias[col];
                #pragma unroll
                for (int r = 0; r < 4; ++r) {
                    float v = acc[fm][fn][r] + bc;
                    v = v > 0.f ? v : 0.f;
                    float hf;
                    ushort hb = bf16_hi_bits(v, &hf);
                    Ohi[(size_t)(rb + r) * N + col] = hb;
                    Olo[(size_t)(rb + r) * N + col] = bf16_bits(v - hf);
                }
            }
        }
    }
}

// ---------------- mid/L6 GEMM (R5-proven): 128x128, wave 64x64, BK=64 --------
__global__ __launch_bounds__(256) void gemm_mid(
    const ushort* __restrict__ Ahi, const ushort* __restrict__ Alo,
    const ushort* __restrict__ Bhi, const ushort* __restrict__ Blo,
    float* __restrict__ OF, int N, int Kfull, int klen)
{
    constexpr int BUF = 65536;
    constexpr int OFF_A[2] = {0, 16384};
    constexpr int OFF_B[2] = {32768, 49152};
    __shared__ char lds[2 * BUF];

    const int tid = threadIdx.x, lane = tid & 63, wid = tid >> 6;

    const int gy = gridDim.y;
    const int nwg = gridDim.x * gy;
    int lin = blockIdx.x * gy + blockIdx.y;
    int q   = nwg >> 3;
    int sw  = (lin & 7) * q + (lin >> 3);
    int bx  = sw / gy, by2 = sw % gy;
    const int bm   = (by2 & 7) << 7;
    const int kz   = by2 >> 3;
    const int kbeg = kz * klen;
    const int bn   = bx << 7;

    const int wm = (wid >> 1) << 6;
    const int wn = (wid & 1) << 6;

    const int ch0 = (lane & 7) ^ (lane >> 3);
    const size_t kstep8 = (size_t)Kfull * 8;
    const ushort* gpb[4];
    uint lob[4];
    {
        const ushort* pls[4] = {Ahi, Alo, Bhi, Blo};
        const int row0s[4]   = {bm, bm, bn, bn};
        const uint bases[4]  = {OFF_A[0], OFF_A[1], OFF_B[0], OFF_B[1]};
        #pragma unroll
        for (int p = 0; p < 4; ++p) {
            gpb[p] = pls[p] + (size_t)(row0s[p] + wid * 32 + (lane >> 3)) * Kfull
                     + kbeg + ch0 * 8;
            lob[p] = bases[p] + wid * 4096;
        }
    }

    uint aoff[4][2], boff[4][2];
    #pragma unroll
    for (int f = 0; f < 4; ++f) {
        #pragma unroll
        for (int ks = 0; ks < 2; ++ks) {
            int ch = (ks * 4 + (lane >> 4)) ^ (lane & 7);
            aoff[f][ks] = OFF_A[0] + (wm + f * 16 + (lane & 15)) * 128 + ch * 16;
            boff[f][ks] = OFF_B[0] + (wn + f * 16 + (lane & 15)) * 128 + ch * 16;
        }
    }

    auto stage = [&](int kt, int b) {
        #pragma unroll
        for (int p = 0; p < 4; ++p)
            #pragma unroll
            for (int i = 0; i < 4; ++i)
                gload_lds16(gpb[p] + i * kstep8 + kt * 64,
                            lds + b * BUF + lob[p] + i * 1024);
    };

    f32x4 acc[4][4] = {};
    const int NT = klen >> 6;

    stage(0, 0);
    __syncthreads();

    for (int t = 0; t < NT; ++t) {
        const int cur = t & 1;
        if (t + 1 < NT) stage(t + 1, cur ^ 1);

        const char* lb = lds + cur * BUF;
        #pragma unroll
        for (int ks = 0; ks < 2; ++ks) {
            bf16x8 aH[4], aL[4], bH[4], bL[4];
            #pragma unroll
            for (int f = 0; f < 4; ++f) {
                aH[f] = *(const bf16x8*)(lb + aoff[f][ks]);
                aL[f] = *(const bf16x8*)(lb + aoff[f][ks] + 16384);
                bH[f] = *(const bf16x8*)(lb + boff[f][ks]);
                bL[f] = *(const bf16x8*)(lb + boff[f][ks] + 16384);
            }
            #pragma unroll
            for (int fm = 0; fm < 4; ++fm)
                #pragma unroll
                for (int fn = 0; fn < 4; ++fn)
                    acc[fm][fn] = __builtin_amdgcn_mfma_f32_16x16x32_bf16(
                        aH[fm], bH[fn], acc[fm][fn], 0, 0, 0);
            #pragma unroll
            for (int fm = 0; fm < 4; ++fm)
                #pragma unroll
                for (int fn = 0; fn < 4; ++fn)
                    acc[fm][fn] = __builtin_amdgcn_mfma_f32_16x16x32_bf16(
                        aH[fm], bL[fn], acc[fm][fn], 0, 0, 0);
            #pragma unroll
            for (int fm = 0; fm < 4; ++fm)
                #pragma unroll
                for (int fn = 0; fn < 4; ++fn)
                    acc[fm][fn] = __builtin_amdgcn_mfma_f32_16x16x32_bf16(
                        aL[fm], bH[fn], acc[fm][fn], 0, 0, 0);
        }
        __syncthreads();
    }

    #pragma unroll
    for (int fm = 0; fm < 4; ++fm) {
        #pragma unroll
        for (int fn = 0; fn < 4; ++fn) {
            const int col = bn + wn + fn * 16 + (lane & 15);
            const int rb  = bm + wm + fm * 16 + ((lane >> 4) << 2);
            #pragma unroll
            for (int r = 0; r < 4; ++r)
                OF[(size_t)(kz * B_ROWS + rb + r) * N + col] = acc[fm][fn][r];
        }
    }
}

// ---------------- mid combine: h = relu(p0+p1+bias) -> hi/lo planes ----------
__global__ __launch_bounds__(256) void combine_mid(
    const float* __restrict__ part, const float* __restrict__ bias,
    ushort* __restrict__ hi, ushort* __restrict__ lo)
{
    const int i = blockIdx.x * 256 + threadIdx.x;     // over 524288 float4
    const float4* p = (const float4*)part;
    float4 a = p[i], b = p[i + 524288];
    float4 bb = ((const float4*)bias)[i & 511];
    float f[4] = {a.x + b.x + bb.x, a.y + b.y + bb.y,
                  a.z + b.z + bb.z, a.w + b.w + bb.w};
    ushort hh[4], ll[4];
    #pragma unroll
    for (int c = 0; c < 4; ++c) {
        float v = f[c] > 0.f ? f[c] : 0.f;
        float hf;
        hh[c] = bf16_hi_bits(v, &hf);
        ll[c] = bf16_bits(v - hf);
    }
    ushort4 h4 = {hh[0], hh[1], hh[2], hh[3]};
    ushort4 l4 = {ll[0], ll[1], ll[2], ll[3]};
    reinterpret_cast<ushort4*>(hi)[i] = h4;
    reinterpret_cast<ushort4*>(lo)[i] = l4;
}

// ---------------- L6 combine: out = relu(sum_8 partial + bias) ---------------
__global__ __launch_bounds__(256) void combine_relu(
    const float* __restrict__ part, const float* __restrict__ bias,
    float* __restrict__ out)
{
    const int i = blockIdx.x * 256 + threadIdx.x;     // over 131072 float4
    const float4* p = (const float4*)part;
    float4 bb = ((const float4*)bias)[i & 127];
    float ox = bb.x, oy = bb.y, oz = bb.z, ow = bb.w;
    #pragma unroll
    for (int z = 0; z < 8; ++z) {
        float4 a = p[i + z * 131072];
        ox += a.x; oy += a.y; oz += a.z; ow += a.w;
    }
    float4 o;
    o.x = ox > 0.f ? ox : 0.f;
    o.y = oy > 0.f ? oy : 0.f;
    o.z = oz > 0.f ? oz : 0.f;
    o.w = ow > 0.f ? ow : 0.f;
    reinterpret_cast<float4*>(out)[i] = o;
}

// ---------------------------------------------------------------------------
extern "C" void kernel_launch(void* const* d_in, const int* in_sizes, int n_in,
                              void* d_out, int out_size, void* d_ws, size_t ws_size,
                              hipStream_t stream)
{
    const float* x     = (const float*)d_in[0];
    const float* emb_W = (const float*)d_in[1];
    const float* W_in  = (const float*)d_in[2];
    const float* b_in  = (const float*)d_in[3];
    const float* W_h   = (const float*)d_in[4];
    const float* b_h   = (const float*)d_in[5];
    const float* W_out = (const float*)d_in[6];
    const float* b_out = (const float*)d_in[7];
    float* out = (float*)d_out;

    char* w = (char*)d_ws;
    const size_t MB = 1 << 20;
    // phase-overlapped region [0..16MB)
    ushort* qhi    = (ushort*)(w);            // 1MB   (phase 1)
    ushort* wihi   = (ushort*)(w + 1*MB);     // 2MB   (phase 1)
    ushort* wilo   = (ushort*)(w + 3*MB);     // 2MB   (phase 1)
    float*  midpar = (float*)(w);             // 16MB  (phase 2: p0@0, p1@8MB)
    ushort* wohi   = (ushort*)(w);            // 2MB   (phase 3)
    ushort* wolo   = (ushort*)(w + 2*MB);     // 2MB   (phase 3)
    // persistent
    ushort* hhi    = (ushort*)(w + 16*MB);    // 4MB
    ushort* hlo    = (ushort*)(w + 20*MB);    // 4MB
    ushort* whhi   = (ushort*)(w + 24*MB);    // 8MB (dead after mids)
    ushort* whlo   = (ushort*)(w + 32*MB);    // 8MB (dead after mids)
    float*  l6par  = (float*)(w + 24*MB);     // 16MB (phase 3, reuses whh/whl)

    // 1) quantize + wi/wh split (fused); writes loss scalar at out[NTOT]
    fused_pre<<<2304, 256, 0, stream>>>(x, emb_W, W_in, W_h,
                                        qhi, wihi, wilo, whhi, whlo, out + NTOT);

    // 2) L1: h = relu(q @ W_in^T + b_in)  M=1024 N=2048 K=512 (A exact, 2-term)
    gemm_split<false, false><<<dim3(16, 16), 256, 0, stream>>>(
        qhi, nullptr, wihi, wilo, b_in, hhi, hlo, nullptr, HDIM, D_IN, D_IN);

    // 3) 4x mid: partial = h @ W_h^T (splitK2, 256 blocks), combine -> h planes
    for (int l = 0; l < 4; ++l) {
        gemm_mid<<<dim3(16, 16), 256, 0, stream>>>(
            hhi, hlo, whhi, whlo, midpar, HDIM, HDIM, 1024);
        combine_mid<<<2048, 256, 0, stream>>>(midpar, b_h, hhi, hlo);
    }

    // 4) split W_out into freed phase-3 region
    wo_split<<<256, 256, 0, stream>>>(W_out, wohi, wolo);

    // 5) L6: partial = h @ W_out^T (splitK8, 256 blocks)  M=1024 N=512 K=2048
    gemm_mid<<<dim3(4, 64), 256, 0, stream>>>(
        hhi, hlo, wohi, wolo, l6par, D_IN, HDIM, 256);

    // 6) combine 8 partials + bias + relu -> d_out
    combine_relu<<<512, 256, 0, stream>>>(l6par, b_out, out);
}